// Round 13
// baseline (190.880 us; speedup 1.0000x reference)
//
#include <hip/hip_runtime.h>
#include <hip/hip_fp16.h>

// CIN (xDeepFM), B=4096, F=32, D=64, layers 128/128.
// Per row m=(b,d): t = x[b,:,d] (32 f32)
//   layer0: y0[o] = relu(b0[o] + sum_{h,f} w0[o, h*32+f] t[h] t[f])
//   hidden = y0[0:64]; direct0 = y0[64:128]
//   layer1: y1[o] = relu(b1[o] + sum_{hh,f} w1[o, hh*32+f] hidden[hh] t[f])
//   out[b] = concat(direct0, y1) summed over d  -> (4096, 192) f32
//
// MFMA mapping (v_mfma_f32_16x16x32_f16):
//   A frag: lane holds A[m = l&15][k = (l>>4)*8 + j]
//   B frag: lane holds B[k = (l>>4)*8 + j][n = l&15]
//   C/D   : col = l&15, row = (l>>4)*4 + reg
//
// Round-22: occupancy is the only untested axis; blocker was the 128-reg
// accumulator (108 arch + 128 acc = 236/wave -> 2 waves/SIMD). HALF-B
// SPLIT: two waves share one b; each owns 4 n-tiles. acc 128->64 AGPR,
// Bf 32->16 VGPR, arch ~90 -> total ~155 -> floor(512/155) = 3 waves/
// SIMD (3 blocks/CU; LDS 48KB*3 = 144KB fits). Schedule = R6's proven
// 48x2-chunk phases verbatim. Boundary is now cross-wave in the pair
// (nh=0 writes hidden, nh=1 writes direct0) -> one extra barrier there.
// (256,2) launch bounds: the only spill-safe declaration (R7/R9/R11/R12
// all spilled under higher min-wave args); occupancy decided by actual
// register allocation.

typedef __attribute__((ext_vector_type(8))) _Float16 f16x8;
typedef __attribute__((ext_vector_type(4))) float f32x4;
typedef __attribute__((ext_vector_type(4))) unsigned short us4;
typedef unsigned short ushortT;

// hidden-table swizzled index: (o,d) -> o*64 + (d ^ ((o&7)<<3))
__device__ __forceinline__ int hidx(int o, int d) {
    return o * 64 + (d ^ ((o & 7) << 3));
}

// ---------- weight pre-pack: f32 -> f16 in B-fragment order ----------
// Stream chunk ktg (8192 B = 4096 ushorts): frag (ktg, n) at ushort
// offset ktg*4096 + n*512 + l*8.
// ktg<32 -> w0 kt=ktg; ktg>=32 -> w1 kt=ktg-32 (contiguous: 32*4096=131072).
__global__ void cin_pack_w(const float* __restrict__ w0,
                           const float* __restrict__ w1,
                           ushortT* __restrict__ wp) {
    int gidx = blockIdx.x * 256 + threadIdx.x;
    if (gidx >= 49152) return;
    const float* src;
    ushortT* dst;
    if (gidx < 16384) {
        int kk = gidx >> 9, rem = gidx & 511;
        int n = rem >> 6, lp = rem & 63;
        int o = n * 16 + (lp & 15);
        int c = kk * 32 + ((lp >> 4) << 3);
        src = w0 + o * 1024 + c;
        dst = wp + gidx * 8;
    } else {
        int g1 = gidx - 16384;
        int kk = g1 >> 9, rem = g1 & 511;
        int n = rem >> 6, lp = rem & 63;
        int o = n * 16 + (lp & 15);
        int c = kk * 32 + ((lp >> 4) << 3);
        src = w1 + o * 2048 + c;
        dst = wp + 131072 + g1 * 8;
    }
    ushortT tmp[8];
#pragma unroll
    for (int j = 0; j < 8; ++j) {
        __half h = __float2half(src[j]);
        tmp[j] = __builtin_bit_cast(ushortT, h);
    }
    *reinterpret_cast<f16x8*>(dst) = *reinterpret_cast<const f16x8*>(tmp);
}

__global__ __launch_bounds__(256, 2) void cin_mfma_kernel(
    const float* __restrict__ x,      // [4096][32][64]
    const float* __restrict__ b0,     // [128]
    const float* __restrict__ b1,     // [128]
    const ushortT* __restrict__ wp,   // packed weights (f16 bits)
    float* __restrict__ out)          // [4096][192]
{
    const int tid  = threadIdx.x;
    const int l    = tid & 63;        // lane
    const int w    = tid >> 6;        // wave 0..3
    const int pair = w >> 1;          // 0,1 -> b = blockIdx*2 + pair
    const int nh   = w & 1;           // n-half: owns n-tiles nh*4 .. nh*4+3
    const int b    = blockIdx.x * 2 + pair;
    const int r16  = l & 15;
    const int g    = l >> 4;

    // Per-PAIR union buffer (8KB): x rows 0..31 (linear, stride 64) during
    // layer 0; hidden rows 0..63 (XOR-swizzled) after the boundary.
    __shared__ ushortT U[2][4096];                    // 16 KB
    __shared__ __align__(16) ushortT Wb[2][8192];     // pair dbuf (32 KB)

    ushortT* Xw = U[pair];   // shared by the 2 waves of this pair

    // ---- prologue: x (f32) -> f16 table (each wave fills half) ----
    const float* xb = x + (size_t)b * 2048;
#pragma unroll
    for (int i = 0; i < 4; ++i) {
        const int idx = (nh * 4 + i) * 64 + l;
        float4 v = reinterpret_cast<const float4*>(xb)[idx];
        us4 h;
        h[0] = __builtin_bit_cast(ushortT, __float2half(v.x));
        h[1] = __builtin_bit_cast(ushortT, __float2half(v.y));
        h[2] = __builtin_bit_cast(ushortT, __float2half(v.z));
        h[3] = __builtin_bit_cast(ushortT, __float2half(v.w));
        *reinterpret_cast<us4*>(&Xw[idx * 4]) = h;
    }

    // ---- stage pair 0 (chunks 0,1 = 16 KB) into slot 0: 4 x 1 KB/wave ----
#pragma unroll
    for (int j = 0; j < 4; ++j) {
        const int seg = w * 4 + j;      // 0..15
        const char* src = (const char*)wp + (size_t)seg * 1024 + (size_t)l * 16;
        __builtin_amdgcn_global_load_lds((const unsigned int*)src,
                                         (unsigned int*)&Wb[0][seg * 512], 16, 0, 0);
    }
    __syncthreads();   // drains vmcnt (pair 0) + lgkm (Xw fill)

    // ---- base T-fragments: tf16[mt][p] = (t[d][g*8+2p], t[d][g*8+2p+1]) ----
    __half2 tf16[4][4];
#pragma unroll
    for (int mt = 0; mt < 4; ++mt)
#pragma unroll
        for (int p = 0; p < 4; ++p) {
            unsigned lo = Xw[(g * 8 + 2 * p) * 64 + mt * 16 + r16];
            unsigned hi = Xw[(g * 8 + 2 * p + 1) * 64 + mt * 16 + r16];
            tf16[mt][p] = __builtin_bit_cast(__half2, lo | (hi << 16));
        }

    f32x4 acc[4][4];   // [mt][n-local] -> 64 accumulator regs
#pragma unroll
    for (int mt = 0; mt < 4; ++mt)
#pragma unroll
        for (int n = 0; n < 4; ++n) acc[mt][n] = (f32x4){0.f, 0.f, 0.f, 0.f};

    union AfU { __half2 h2[4]; f16x8 v; };

    // th for chunk 0, carried across phases in registers
    __half2 thc[4];
#pragma unroll
    for (int mt = 0; mt < 4; ++mt) {
        unsigned u = Xw[mt * 16 + r16];
        thc[mt] = __builtin_bit_cast(__half2, (u << 16) | u);
    }

    const int nb = nh * 4;   // this wave's global n-tile base

    // ---------------- phase loop: 48 phases x 2 chunks (R6 schedule) ----
#pragma unroll 1
    for (int p = 0; p < 48; ++p) {
        const int ps = p & 1;
        const int k0 = 2 * p;
        const int k1 = k0 + 1;

        // stage next pair (issued first; lands during this phase body)
        if (p + 1 < 48) {
#pragma unroll
            for (int j = 0; j < 4; ++j) {
                const int seg = w * 4 + j;
                const char* src = (const char*)wp + (size_t)(p + 1) * 16384 +
                                  (size_t)seg * 1024 + (size_t)l * 16;
                __builtin_amdgcn_global_load_lds((const unsigned int*)src,
                    (unsigned int*)&Wb[ps ^ 1][seg * 512], 16, 0, 0);
            }
        }

        // B-frags for chunk k0 (this wave's 4 n-tiles)
        f16x8 Bf[4];
#pragma unroll
        for (int n = 0; n < 4; ++n)
            Bf[n] = *reinterpret_cast<const f16x8*>(
                &Wb[ps][(nb + n) * 512 + l * 8]);

        // Af for chunk k0 from carried thc (no LDS on this chain)
        AfU Af[4];
#pragma unroll
        for (int mt = 0; mt < 4; ++mt)
#pragma unroll
            for (int q = 0; q < 4; ++q)
                Af[mt].h2[q] = __hmul2(tf16[mt][q], thc[mt]);

        // th for chunk k1 (x rows linear; hidden rows swizzled)
        __half2 th1[4];
#pragma unroll
        for (int mt = 0; mt < 4; ++mt) {
            const int c = mt * 16 + r16;
            unsigned u = (k1 < 32) ? Xw[k1 * 64 + c] : Xw[hidx(k1 - 32, c)];
            th1[mt] = __builtin_bit_cast(__half2, (u << 16) | u);
        }

        // burst 0 (16 MFMAs); Bf[n] reloaded for chunk k1 after last use
        __builtin_amdgcn_s_setprio(1);
#pragma unroll
        for (int n = 0; n < 4; ++n) {
#pragma unroll
            for (int mt = 0; mt < 4; ++mt)
                acc[mt][n] = __builtin_amdgcn_mfma_f32_16x16x32_f16(
                    Af[mt].v, Bf[n], acc[mt][n], 0, 0, 0);
            Bf[n] = *reinterpret_cast<const f16x8*>(
                &Wb[ps][4096 + (nb + n) * 512 + l * 8]);
        }
        __builtin_amdgcn_s_setprio(0);

        // Af for chunk k1 (th1 landed during burst 0)
#pragma unroll
        for (int mt = 0; mt < 4; ++mt)
#pragma unroll
            for (int q = 0; q < 4; ++q)
                Af[mt].h2[q] = __hmul2(tf16[mt][q], th1[mt]);

        // burst 1 (16 MFMAs)
        __builtin_amdgcn_s_setprio(1);
#pragma unroll
        for (int n = 0; n < 4; ++n)
#pragma unroll
            for (int mt = 0; mt < 4; ++mt)
                acc[mt][n] = __builtin_amdgcn_mfma_f32_16x16x32_f16(
                    Af[mt].v, Bf[n], acc[mt][n], 0, 0, 0);
        __builtin_amdgcn_s_setprio(0);

        // prefetch th for next phase's k0 (table reads only; hazard-free
        // across the barrier; p==15 value garbage, recomputed at boundary)
        if (p + 1 < 48) {
            const int k2 = k0 + 2;
#pragma unroll
            for (int mt = 0; mt < 4; ++mt) {
                const int c = mt * 16 + r16;
                unsigned u = (k2 < 32) ? Xw[k2 * 64 + c] : Xw[hidx(k2 - 32, c)];
                thc[mt] = __builtin_bit_cast(__half2, (u << 16) | u);
            }
        }

        __syncthreads();   // pair p+1 landed; all reads of slot ps done

        // layer boundary after phase 15 (chunks 30,31 complete layer 0)
        if (p == 15) {
            ushortT* Hw = Xw;   // union: x rows dead from here on
            if (nh == 0) {
                // this wave's n-tiles are channels 0..63 -> hidden table
#pragma unroll
                for (int n = 0; n < 4; ++n) {
                    float bn = b0[n * 16 + r16];
                    const int o = n * 16 + r16;
#pragma unroll
                    for (int mt = 0; mt < 4; ++mt) {
                        us4 hv;
#pragma unroll
                        for (int r = 0; r < 4; ++r) {
                            float y = fmaxf(acc[mt][n][r] + bn, 0.f);
                            hv[r] = __builtin_bit_cast(ushortT, __float2half(y));
                        }
                        *reinterpret_cast<us4*>(&Hw[hidx(o, mt * 16 + g * 4)]) = hv;
                    }
                }
            } else {
                // channels 64..127 -> layer-0 direct outputs
#pragma unroll
                for (int n = 0; n < 4; ++n) {
                    float bn = b0[64 + n * 16 + r16];
                    float s = 0.f;
#pragma unroll
                    for (int mt = 0; mt < 4; ++mt)
#pragma unroll
                        for (int r = 0; r < 4; ++r)
                            s += fmaxf(acc[mt][n][r] + bn, 0.f);
                    s += __shfl_xor(s, 16);
                    s += __shfl_xor(s, 32);
                    if (l < 16) out[(size_t)b * 192 + n * 16 + l] = s;
                }
            }
#pragma unroll
            for (int mt = 0; mt < 4; ++mt)
#pragma unroll
                for (int n = 0; n < 4; ++n) acc[mt][n] = (f32x4){0.f, 0.f, 0.f, 0.f};

            __syncthreads();   // hidden visible to BOTH waves of the pair

            // th for chunk 32 = hidden row 0
#pragma unroll
            for (int mt = 0; mt < 4; ++mt) {
                unsigned u = Hw[hidx(0, mt * 16 + r16)];
                thc[mt] = __builtin_bit_cast(__half2, (u << 16) | u);
            }
        }
    }

    // layer-1 epilogue: this wave's 4 n-tiles -> channels 64 + (nb+n)*16
#pragma unroll
    for (int n = 0; n < 4; ++n) {
        float bn = b1[(nb + n) * 16 + r16];
        float s = 0.f;
#pragma unroll
        for (int mt = 0; mt < 4; ++mt)
#pragma unroll
            for (int r = 0; r < 4; ++r)
                s += fmaxf(acc[mt][n][r] + bn, 0.f);
        s += __shfl_xor(s, 16);
        s += __shfl_xor(s, 32);
        if (l < 16) out[(size_t)b * 192 + 64 + (nb + n) * 16 + l] = s;
    }
}

// ---------- fp32 fallback, used only if ws too small ------
__global__ __launch_bounds__(256, 4) void cin_fp32_kernel(
    const float* __restrict__ x, const float* __restrict__ w0,
    const float* __restrict__ b0, const float* __restrict__ w1,
    const float* __restrict__ b1, float* __restrict__ out)
{
    const int b = blockIdx.x;
    const int tid = threadIdx.x;
    const int d = tid & 63;
    const int wave = tid >> 6;

    __shared__ float Xs[32][64];
    __shared__ float Hsf[64][64];

    const float* xb = x + (size_t)b * 2048;
    float treg[32];
#pragma unroll
    for (int f = 0; f < 32; ++f) treg[f] = xb[f * 64 + d];
    if (wave == 0) {
#pragma unroll
        for (int f = 0; f < 32; ++f) Xs[f][d] = treg[f];
    }
    __syncthreads();
    const int o_base = __builtin_amdgcn_readfirstlane(wave * 32);

    for (int oi = 0; oi < 32; ++oi) {
        const int o = o_base + oi;
        const float* wrow = w0 + (size_t)o * 1024;
        float acc = b0[o];
        for (int h = 0; h < 32; ++h) {
            const float* wv = wrow + h * 32;
            const float th = Xs[h][d];
            float s0 = 0.f, s1 = 0.f, s2 = 0.f, s3 = 0.f;
#pragma unroll
            for (int f = 0; f < 32; f += 4) {
                s0 = fmaf(wv[f + 0], treg[f + 0], s0);
                s1 = fmaf(wv[f + 1], treg[f + 1], s1);
                s2 = fmaf(wv[f + 2], treg[f + 2], s2);
                s3 = fmaf(wv[f + 3], treg[f + 3], s3);
            }
            acc = fmaf((s0 + s1) + (s2 + s3), th, acc);
        }
        float y = fmaxf(acc, 0.f);
        if (o < 64) {
            Hsf[o][d] = y;
        } else {
#pragma unroll
            for (int off = 32; off > 0; off >>= 1) y += __shfl_xor(y, off, 64);
            if (d == 0) out[(size_t)b * 192 + (o - 64)] = y;
        }
    }
    __syncthreads();

    for (int oi = 0; oi < 32; ++oi) {
        const int o = o_base + oi;
        const float* wrow = w1 + (size_t)o * 2048;
        float acc = b1[o];
        for (int h = 0; h < 64; ++h) {
            const float* wv = wrow + h * 32;
            const float th = Hsf[h][d];
            float s0 = 0.f, s1 = 0.f, s2 = 0.f, s3 = 0.f;
#pragma unroll
            for (int f = 0; f < 32; f += 4) {
                s0 = fmaf(wv[f + 0], treg[f + 0], s0);
                s1 = fmaf(wv[f + 1], treg[f + 1], s1);
                s2 = fmaf(wv[f + 2], treg[f + 2], s2);
                s3 = fmaf(wv[f + 3], treg[f + 3], s3);
            }
            acc = fmaf((s0 + s1) + (s2 + s3), th, acc);
        }
        float y = fmaxf(acc, 0.f);
#pragma unroll
        for (int off = 32; off > 0; off >>= 1) y += __shfl_xor(y, off, 64);
        if (d == 0) out[(size_t)b * 192 + 64 + o] = y;
    }
}

extern "C" void kernel_launch(void* const* d_in, const int* in_sizes, int n_in,
                              void* d_out, int out_size, void* d_ws, size_t ws_size,
                              hipStream_t stream) {
    const float* x  = (const float*)d_in[0];
    const float* w0 = (const float*)d_in[1];
    const float* b0 = (const float*)d_in[2];
    const float* w1 = (const float*)d_in[3];
    const float* b1 = (const float*)d_in[4];
    float* out = (float*)d_out;

    if (ws_size >= 786432) {
        ushortT* wp = (ushortT*)d_ws;
        cin_pack_w<<<192, 256, 0, stream>>>(w0, w1, wp);
        cin_mfma_kernel<<<2048, 256, 0, stream>>>(x, b0, b1, wp, out);
    } else {
        cin_fp32_kernel<<<4096, 256, 0, stream>>>(x, w0, b0, w1, b1, out);
    }
}

// Round 14
// 185.688 us; speedup vs baseline: 1.0280x; 1.0280x over previous
//
#include <hip/hip_runtime.h>
#include <hip/hip_fp16.h>

// CIN (xDeepFM), B=4096, F=32, D=64, layers 128/128.
// Per row m=(b,d): t = x[b,:,d] (32 f32)
//   layer0: y0[o] = relu(b0[o] + sum_{h,f} w0[o, h*32+f] t[h] t[f])
//   hidden = y0[0:64]; direct0 = y0[64:128]
//   layer1: y1[o] = relu(b1[o] + sum_{hh,f} w1[o, hh*32+f] hidden[hh] t[f])
//   out[b] = concat(direct0, y1) summed over d  -> (4096, 192) f32
//
// MFMA mapping (v_mfma_f32_16x16x32_f16):
//   A frag: lane holds A[m = l&15][k = (l>>4)*8 + j]
//   B frag: lane holds B[k = (l>>4)*8 + j][n = l&15]
//   C/D   : col = l&15, row = (l>>4)*4 + reg
//
// Round-23: R22's n-split raised occupancy (22->30) but VALUBusy doubled
// (31->53) and util FELL: the Af build (per-m VALU) was duplicated, not
// split, so hmul2:MFMA doubled. M-SPLIT instead: 2 waves share one b,
// each owns 2 of 4 mt tiles (a d-half) and ALL 8 n-tiles. Af/th/tf16
// halve per wave (ratio back to R6's 0.5 hmul2/MFMA); duplicated part is
// only the Bf LDS reads (1.5x LDS traffic vs R6 -- known risk). acc 64,
// arch ~90 -> ~155/wave -> 3 waves/SIMD. LDS 49KB -> 3 blocks/CU.
// Direct-output sums now span the pair's two d-halves -> 1KB LDS
// partial-sum scratch at boundary + epilogue. Schedule = R6 verbatim.

typedef __attribute__((ext_vector_type(8))) _Float16 f16x8;
typedef __attribute__((ext_vector_type(4))) float f32x4;
typedef __attribute__((ext_vector_type(4))) unsigned short us4;
typedef unsigned short ushortT;

// hidden-table swizzled index: (o,d) -> o*64 + (d ^ ((o&7)<<3))
__device__ __forceinline__ int hidx(int o, int d) {
    return o * 64 + (d ^ ((o & 7) << 3));
}

// ---------- weight pre-pack: f32 -> f16 in B-fragment order ----------
// Stream chunk ktg (8192 B = 4096 ushorts): frag (ktg, n) at ushort
// offset ktg*4096 + n*512 + l*8.
// ktg<32 -> w0 kt=ktg; ktg>=32 -> w1 kt=ktg-32 (contiguous: 32*4096=131072).
__global__ void cin_pack_w(const float* __restrict__ w0,
                           const float* __restrict__ w1,
                           ushortT* __restrict__ wp) {
    int gidx = blockIdx.x * 256 + threadIdx.x;
    if (gidx >= 49152) return;
    const float* src;
    ushortT* dst;
    if (gidx < 16384) {
        int kk = gidx >> 9, rem = gidx & 511;
        int n = rem >> 6, lp = rem & 63;
        int o = n * 16 + (lp & 15);
        int c = kk * 32 + ((lp >> 4) << 3);
        src = w0 + o * 1024 + c;
        dst = wp + gidx * 8;
    } else {
        int g1 = gidx - 16384;
        int kk = g1 >> 9, rem = g1 & 511;
        int n = rem >> 6, lp = rem & 63;
        int o = n * 16 + (lp & 15);
        int c = kk * 32 + ((lp >> 4) << 3);
        src = w1 + o * 2048 + c;
        dst = wp + 131072 + g1 * 8;
    }
    ushortT tmp[8];
#pragma unroll
    for (int j = 0; j < 8; ++j) {
        __half h = __float2half(src[j]);
        tmp[j] = __builtin_bit_cast(ushortT, h);
    }
    *reinterpret_cast<f16x8*>(dst) = *reinterpret_cast<const f16x8*>(tmp);
}

__global__ __launch_bounds__(256, 2) void cin_mfma_kernel(
    const float* __restrict__ x,      // [4096][32][64]
    const float* __restrict__ b0,     // [128]
    const float* __restrict__ b1,     // [128]
    const ushortT* __restrict__ wp,   // packed weights (f16 bits)
    float* __restrict__ out)          // [4096][192]
{
    const int tid  = threadIdx.x;
    const int l    = tid & 63;        // lane
    const int w    = tid >> 6;        // wave 0..3
    const int pair = w >> 1;          // 0,1 -> b = blockIdx*2 + pair
    const int mh   = w & 1;           // m-half: owns mt = mh*2, mh*2+1
    const int b    = blockIdx.x * 2 + pair;
    const int r16  = l & 15;
    const int g    = l >> 4;

    // Per-PAIR union buffer (8KB): x rows 0..31 (linear, stride 64) during
    // layer 0; hidden rows 0..63 (XOR-swizzled) after the boundary.
    __shared__ ushortT U[2][4096];                    // 16 KB
    __shared__ __align__(16) ushortT Wb[2][8192];     // pair dbuf (32 KB)
    __shared__ float Scr[2][8][16];                   // partial-sum scratch (1 KB)

    ushortT* Xw = U[pair];   // shared by the 2 waves of this pair

    // ---- prologue: x (f32) -> f16 table (each wave fills half) ----
    const float* xb = x + (size_t)b * 2048;
#pragma unroll
    for (int i = 0; i < 4; ++i) {
        const int idx = (mh * 4 + i) * 64 + l;
        float4 v = reinterpret_cast<const float4*>(xb)[idx];
        us4 h;
        h[0] = __builtin_bit_cast(ushortT, __float2half(v.x));
        h[1] = __builtin_bit_cast(ushortT, __float2half(v.y));
        h[2] = __builtin_bit_cast(ushortT, __float2half(v.z));
        h[3] = __builtin_bit_cast(ushortT, __float2half(v.w));
        *reinterpret_cast<us4*>(&Xw[idx * 4]) = h;
    }

    // ---- stage pair 0 (chunks 0,1 = 16 KB) into slot 0: 4 x 1 KB/wave ----
#pragma unroll
    for (int j = 0; j < 4; ++j) {
        const int seg = w * 4 + j;      // 0..15
        const char* src = (const char*)wp + (size_t)seg * 1024 + (size_t)l * 16;
        __builtin_amdgcn_global_load_lds((const unsigned int*)src,
                                         (unsigned int*)&Wb[0][seg * 512], 16, 0, 0);
    }
    __syncthreads();   // drains vmcnt (pair 0) + lgkm (Xw fill)

    // this wave's d-columns: c(mtl) = mh*32 + mtl*16 + r16
    const int c0 = mh * 32 + r16;        // mtl = 0
    const int c1 = mh * 32 + 16 + r16;   // mtl = 1

    // ---- base T-fragments (own 2 mt tiles only) ----
    __half2 tf16[2][4];
#pragma unroll
    for (int mtl = 0; mtl < 2; ++mtl) {
        const int c = (mtl == 0) ? c0 : c1;
#pragma unroll
        for (int p = 0; p < 4; ++p) {
            unsigned lo = Xw[(g * 8 + 2 * p) * 64 + c];
            unsigned hi = Xw[(g * 8 + 2 * p + 1) * 64 + c];
            tf16[mtl][p] = __builtin_bit_cast(__half2, lo | (hi << 16));
        }
    }

    f32x4 acc[2][8];   // [mtl][n] -> 64 accumulator regs
#pragma unroll
    for (int mtl = 0; mtl < 2; ++mtl)
#pragma unroll
        for (int n = 0; n < 8; ++n) acc[mtl][n] = (f32x4){0.f, 0.f, 0.f, 0.f};

    union AfU { __half2 h2[4]; f16x8 v; };

    // th for chunk 0, carried across phases in registers
    __half2 thc[2];
    {
        unsigned u0 = Xw[c0], u1 = Xw[c1];
        thc[0] = __builtin_bit_cast(__half2, (u0 << 16) | u0);
        thc[1] = __builtin_bit_cast(__half2, (u1 << 16) | u1);
    }

    // ---------------- phase loop: 48 phases x 2 chunks (R6 schedule) ----
#pragma unroll 1
    for (int p = 0; p < 48; ++p) {
        const int ps = p & 1;
        const int k0 = 2 * p;
        const int k1 = k0 + 1;

        // stage next pair (issued first; lands during this phase body)
        if (p + 1 < 48) {
#pragma unroll
            for (int j = 0; j < 4; ++j) {
                const int seg = w * 4 + j;
                const char* src = (const char*)wp + (size_t)(p + 1) * 16384 +
                                  (size_t)seg * 1024 + (size_t)l * 16;
                __builtin_amdgcn_global_load_lds((const unsigned int*)src,
                    (unsigned int*)&Wb[ps ^ 1][seg * 512], 16, 0, 0);
            }
        }

        // B-frags for chunk k0 (all 8 n-tiles)
        f16x8 Bf[8];
#pragma unroll
        for (int n = 0; n < 8; ++n)
            Bf[n] = *reinterpret_cast<const f16x8*>(&Wb[ps][n * 512 + l * 8]);

        // Af for chunk k0 from carried thc (8 hmul2)
        AfU Af[2];
#pragma unroll
        for (int mtl = 0; mtl < 2; ++mtl)
#pragma unroll
            for (int q = 0; q < 4; ++q)
                Af[mtl].h2[q] = __hmul2(tf16[mtl][q], thc[mtl]);

        // th for chunk k1 (x rows linear; hidden rows swizzled)
        __half2 th1[2];
        {
            unsigned u0 = (k1 < 32) ? Xw[k1 * 64 + c0] : Xw[hidx(k1 - 32, c0)];
            unsigned u1 = (k1 < 32) ? Xw[k1 * 64 + c1] : Xw[hidx(k1 - 32, c1)];
            th1[0] = __builtin_bit_cast(__half2, (u0 << 16) | u0);
            th1[1] = __builtin_bit_cast(__half2, (u1 << 16) | u1);
        }

        // burst 0 (16 MFMAs); Bf[n] reloaded for chunk k1 after last use
        __builtin_amdgcn_s_setprio(1);
#pragma unroll
        for (int n = 0; n < 8; ++n) {
#pragma unroll
            for (int mtl = 0; mtl < 2; ++mtl)
                acc[mtl][n] = __builtin_amdgcn_mfma_f32_16x16x32_f16(
                    Af[mtl].v, Bf[n], acc[mtl][n], 0, 0, 0);
            Bf[n] = *reinterpret_cast<const f16x8*>(
                &Wb[ps][4096 + n * 512 + l * 8]);
        }
        __builtin_amdgcn_s_setprio(0);

        // Af for chunk k1 (th1 landed during burst 0)
#pragma unroll
        for (int mtl = 0; mtl < 2; ++mtl)
#pragma unroll
            for (int q = 0; q < 4; ++q)
                Af[mtl].h2[q] = __hmul2(tf16[mtl][q], th1[mtl]);

        // burst 1 (16 MFMAs)
        __builtin_amdgcn_s_setprio(1);
#pragma unroll
        for (int n = 0; n < 8; ++n)
#pragma unroll
            for (int mtl = 0; mtl < 2; ++mtl)
                acc[mtl][n] = __builtin_amdgcn_mfma_f32_16x16x32_f16(
                    Af[mtl].v, Bf[n], acc[mtl][n], 0, 0, 0);
        __builtin_amdgcn_s_setprio(0);

        // prefetch th for next phase's k0 (pair-shared table: hazard-free
        // across the barrier; p==15 value garbage, recomputed at boundary)
        if (p + 1 < 48) {
            const int k2 = k0 + 2;
            unsigned u0 = (k2 < 32) ? Xw[k2 * 64 + c0] : Xw[hidx(k2 - 32, c0)];
            unsigned u1 = (k2 < 32) ? Xw[k2 * 64 + c1] : Xw[hidx(k2 - 32, c1)];
            thc[0] = __builtin_bit_cast(__half2, (u0 << 16) | u0);
            thc[1] = __builtin_bit_cast(__half2, (u1 << 16) | u1);
        }

        __syncthreads();   // pair p+1 landed; all reads of slot ps done

        // layer boundary after phase 15 (chunks 30,31 complete layer 0)
        if (p == 15) {
            ushortT* Hw = Xw;   // union: x rows dead from here on
            // hidden channels 0..63 (n 0..3), this wave's d-half
#pragma unroll
            for (int n = 0; n < 4; ++n) {
                float bn = b0[n * 16 + r16];
                const int o = n * 16 + r16;
#pragma unroll
                for (int mtl = 0; mtl < 2; ++mtl) {
                    us4 hv;
#pragma unroll
                    for (int r = 0; r < 4; ++r) {
                        float y = fmaxf(acc[mtl][n][r] + bn, 0.f);
                        hv[r] = __builtin_bit_cast(ushortT, __float2half(y));
                    }
                    const int d0 = mh * 32 + mtl * 16 + g * 4;
                    *reinterpret_cast<us4*>(&Hw[hidx(o, d0)]) = hv;
                }
            }
            // direct0 (channels 64..127, n 4..7): partial over this d-half
            float sdir[4];
#pragma unroll
            for (int n = 4; n < 8; ++n) {
                float bn = b0[64 + (n - 4) * 16 + r16];
                float s = 0.f;
#pragma unroll
                for (int mtl = 0; mtl < 2; ++mtl)
#pragma unroll
                    for (int r = 0; r < 4; ++r)
                        s += fmaxf(acc[mtl][n][r] + bn, 0.f);
                s += __shfl_xor(s, 16);
                s += __shfl_xor(s, 32);
                sdir[n - 4] = s;
                if (mh == 1 && l < 16) Scr[pair][n][l] = s;
            }
            __syncthreads();   // hidden + partials visible pair-wide
            if (mh == 0 && l < 16) {
#pragma unroll
                for (int n = 4; n < 8; ++n)
                    out[(size_t)b * 192 + (n - 4) * 16 + l] =
                        sdir[n - 4] + Scr[pair][n][l];
            }
#pragma unroll
            for (int mtl = 0; mtl < 2; ++mtl)
#pragma unroll
                for (int n = 0; n < 8; ++n) acc[mtl][n] = (f32x4){0.f, 0.f, 0.f, 0.f};
            // th for chunk 32 = hidden row 0
            unsigned u0 = Hw[hidx(0, c0)], u1 = Hw[hidx(0, c1)];
            thc[0] = __builtin_bit_cast(__half2, (u0 << 16) | u0);
            thc[1] = __builtin_bit_cast(__half2, (u1 << 16) | u1);
        }
    }

    // layer-1 epilogue: all 8 n-tiles, partial over this wave's d-half
    {
        float sv[8];
#pragma unroll
        for (int n = 0; n < 8; ++n) {
            float bn = b1[n * 16 + r16];
            float s = 0.f;
#pragma unroll
            for (int mtl = 0; mtl < 2; ++mtl)
#pragma unroll
                for (int r = 0; r < 4; ++r)
                    s += fmaxf(acc[mtl][n][r] + bn, 0.f);
            s += __shfl_xor(s, 16);
            s += __shfl_xor(s, 32);
            sv[n] = s;
            if (mh == 1 && l < 16) Scr[pair][n][l] = s;
        }
        __syncthreads();
        if (mh == 0 && l < 16) {
#pragma unroll
            for (int n = 0; n < 8; ++n)
                out[(size_t)b * 192 + 64 + n * 16 + l] = sv[n] + Scr[pair][n][l];
        }
    }
}

// ---------- fp32 fallback, used only if ws too small ------
__global__ __launch_bounds__(256, 4) void cin_fp32_kernel(
    const float* __restrict__ x, const float* __restrict__ w0,
    const float* __restrict__ b0, const float* __restrict__ w1,
    const float* __restrict__ b1, float* __restrict__ out)
{
    const int b = blockIdx.x;
    const int tid = threadIdx.x;
    const int d = tid & 63;
    const int wave = tid >> 6;

    __shared__ float Xs[32][64];
    __shared__ float Hsf[64][64];

    const float* xb = x + (size_t)b * 2048;
    float treg[32];
#pragma unroll
    for (int f = 0; f < 32; ++f) treg[f] = xb[f * 64 + d];
    if (wave == 0) {
#pragma unroll
        for (int f = 0; f < 32; ++f) Xs[f][d] = treg[f];
    }
    __syncthreads();
    const int o_base = __builtin_amdgcn_readfirstlane(wave * 32);

    for (int oi = 0; oi < 32; ++oi) {
        const int o = o_base + oi;
        const float* wrow = w0 + (size_t)o * 1024;
        float acc = b0[o];
        for (int h = 0; h < 32; ++h) {
            const float* wv = wrow + h * 32;
            const float th = Xs[h][d];
            float s0 = 0.f, s1 = 0.f, s2 = 0.f, s3 = 0.f;
#pragma unroll
            for (int f = 0; f < 32; f += 4) {
                s0 = fmaf(wv[f + 0], treg[f + 0], s0);
                s1 = fmaf(wv[f + 1], treg[f + 1], s1);
                s2 = fmaf(wv[f + 2], treg[f + 2], s2);
                s3 = fmaf(wv[f + 3], treg[f + 3], s3);
            }
            acc = fmaf((s0 + s1) + (s2 + s3), th, acc);
        }
        float y = fmaxf(acc, 0.f);
        if (o < 64) {
            Hsf[o][d] = y;
        } else {
#pragma unroll
            for (int off = 32; off > 0; off >>= 1) y += __shfl_xor(y, off, 64);
            if (d == 0) out[(size_t)b * 192 + (o - 64)] = y;
        }
    }
    __syncthreads();

    for (int oi = 0; oi < 32; ++oi) {
        const int o = o_base + oi;
        const float* wrow = w1 + (size_t)o * 2048;
        float acc = b1[o];
        for (int h = 0; h < 64; ++h) {
            const float* wv = wrow + h * 32;
            const float th = Hsf[h][d];
            float s0 = 0.f, s1 = 0.f, s2 = 0.f, s3 = 0.f;
#pragma unroll
            for (int f = 0; f < 32; f += 4) {
                s0 = fmaf(wv[f + 0], treg[f + 0], s0);
                s1 = fmaf(wv[f + 1], treg[f + 1], s1);
                s2 = fmaf(wv[f + 2], treg[f + 2], s2);
                s3 = fmaf(wv[f + 3], treg[f + 3], s3);
            }
            acc = fmaf((s0 + s1) + (s2 + s3), th, acc);
        }
        float y = fmaxf(acc, 0.f);
#pragma unroll
        for (int off = 32; off > 0; off >>= 1) y += __shfl_xor(y, off, 64);
        if (d == 0) out[(size_t)b * 192 + 64 + o] = y;
    }
}

extern "C" void kernel_launch(void* const* d_in, const int* in_sizes, int n_in,
                              void* d_out, int out_size, void* d_ws, size_t ws_size,
                              hipStream_t stream) {
    const float* x  = (const float*)d_in[0];
    const float* w0 = (const float*)d_in[1];
    const float* b0 = (const float*)d_in[2];
    const float* w1 = (const float*)d_in[3];
    const float* b1 = (const float*)d_in[4];
    float* out = (float*)d_out;

    if (ws_size >= 786432) {
        ushortT* wp = (ushortT*)d_ws;
        cin_pack_w<<<192, 256, 0, stream>>>(w0, w1, wp);
        cin_mfma_kernel<<<2048, 256, 0, stream>>>(x, b0, b1, wp, out);
    } else {
        cin_fp32_kernel<<<4096, 256, 0, stream>>>(x, w0, b0, w1, b1, out);
    }
}